// Round 4
// baseline (38.085 us; speedup 1.0000x reference)
//
#include <hip/hip_runtime.h>

// PS-ROI pooling. inputs: [8,64,64,2304] f32 ; boxes: [8,128,4] f32
// out: [8,128,1,1,256] f32
// One 512-thread block (8 waves) per box; wave w handles sample points
// p (0..80) with p&7 == w; lane owns channels 4*lane..4*lane+3 (float4
// gathers: 16B/lane x 64 lanes = full 1KB channel group per instruction).
// 8192 waves total = 32 waves/CU if VGPR <= 64 (arrays slimmed for that).
// blockIdx & 7 = image index -> image-aligned XCD placement for L2 reuse.

#define BATCH 8
#define NBOX  128
#define IH    64
#define IW    64
#define IC    2304
#define SCH   256   // IC / 9

typedef float f32x4 __attribute__((ext_vector_type(4)));

__global__ __launch_bounds__(512) void psroi_kernel(
    const float* __restrict__ inp,
    const float* __restrict__ boxes,
    float* __restrict__ out)
{
    const int blk  = blockIdx.x;
    const int b    = blk & 7;      // image  (XCD-aligned)
    const int n    = blk >> 3;     // box within image
    const int box  = b * NBOX + n;
    const int tid  = threadIdx.x;
    const int lane = tid & 63;     // channel group: 4*lane..4*lane+3
    const int w    = tid >> 6;     // wave 0..7 -> sample-point stripe

    const float* bp = boxes + (size_t)box * 4;
    const float y1 = bp[0];
    const float x1 = bp[1];
    const float y2 = bp[2];
    const float x2 = bp[3];

    const float sy = (y2 - y1) * (1.0f / 3.0f);
    const float sx = (x2 - x1) * (1.0f / 3.0f);

    // Separable sample coords, slim register footprint:
    // r0[j] = floor-row * IW (premultiplied), c0[j] = floor-col,
    // ly/lx = lerp weights, validity packed into bitmasks.
    int   r0[9], c0[9];
    float ly[9], lx[9];
    unsigned vym = 0u, vxm = 0u;

    #pragma unroll
    for (int byi = 0; byi < 3; ++byi) {
        #pragma unroll
        for (int i = 0; i < 3; ++i) {
            const int j = byi * 3 + i;
            float ys = (y1 + (float)byi * sy) * 63.0f + (float)i * sy * 31.5f;
            float xs = (x1 + (float)byi * sx) * 63.0f + (float)i * sx * 31.5f;
            if (ys >= 0.0f && ys <= 63.0f) vym |= (1u << j);
            if (xs >= 0.0f && xs <= 63.0f) vxm |= (1u << j);
            float ysc = fminf(fmaxf(ys, 0.0f), 63.0f);
            float xsc = fminf(fmaxf(xs, 0.0f), 63.0f);
            float yf = floorf(ysc);
            float xf = floorf(xsc);
            ly[j] = ysc - yf;
            lx[j] = xsc - xf;
            r0[j] = (int)yf * IW;
            c0[j] = (int)xf;
        }
    }

    const float* base = inp + (size_t)b * (IH * IW * IC) + lane * 4;

    f32x4 acc = {0.0f, 0.0f, 0.0f, 0.0f};

    #pragma unroll
    for (int byi = 0; byi < 3; ++byi) {
        #pragma unroll
        for (int bxi = 0; bxi < 3; ++bxi) {
            const int tb = byi * 3 + bxi;
            const float* gbase = base + tb * SCH;
            #pragma unroll
            for (int cy = 0; cy < 3; ++cy) {
                const int jy = byi * 3 + cy;
                #pragma unroll
                for (int cx = 0; cx < 3; ++cx) {
                    const int p = (tb * 3 + cy) * 3 + cx;     // 0..80
                    if ((p & 7) != w) continue;               // wave-uniform stripe
                    const int jx = bxi * 3 + cx;
                    if (((vym >> jy) & (vxm >> jx) & 1u) != 0u) {
                        const int rr0 = r0[jy];
                        const int rr1 = (rr0 + IW < 63 * IW) ? (rr0 + IW) : 63 * IW;
                        const int cc0 = c0[jx];
                        const int cc1 = (cc0 + 1 < 63) ? (cc0 + 1) : 63;
                        const float wy = ly[jy];
                        const float wx = lx[jx];
                        const f32x4 a  = *reinterpret_cast<const f32x4*>(gbase + (size_t)(rr0 + cc0) * IC);
                        const f32x4 bb = *reinterpret_cast<const f32x4*>(gbase + (size_t)(rr0 + cc1) * IC);
                        const f32x4 cc = *reinterpret_cast<const f32x4*>(gbase + (size_t)(rr1 + cc0) * IC);
                        const f32x4 dd = *reinterpret_cast<const f32x4*>(gbase + (size_t)(rr1 + cc1) * IC);
                        const f32x4 top = a  * (1.0f - wx) + bb * wx;
                        const f32x4 bot = cc * (1.0f - wx) + dd * wx;
                        acc += top * (1.0f - wy) + bot * wy;
                    }
                }
            }
        }
    }

    // Reduce 8 waves' partial sums via LDS.
    __shared__ float red[8][SCH];
    *reinterpret_cast<f32x4*>(&red[w][lane * 4]) = acc;
    __syncthreads();

    if (tid < SCH) {
        float v = 0.0f;
        #pragma unroll
        for (int k = 0; k < 8; ++k) v += red[k][tid];
        out[(size_t)box * SCH + tid] = v * (1.0f / 81.0f);
    }
}

extern "C" void kernel_launch(void* const* d_in, const int* in_sizes, int n_in,
                              void* d_out, int out_size, void* d_ws, size_t ws_size,
                              hipStream_t stream) {
    const float* inp   = (const float*)d_in[0];
    const float* boxes = (const float*)d_in[1];
    float* out = (float*)d_out;

    dim3 grid(BATCH * NBOX);
    dim3 block(512);
    psroi_kernel<<<grid, block, 0, stream>>>(inp, boxes, out);
}

// Round 5
// 34.479 us; speedup vs baseline: 1.1046x; 1.1046x over previous
//
#include <hip/hip_runtime.h>

// PS-ROI pooling. inputs: [8,64,64,2304] f32 ; boxes: [8,128,4] f32
// out: [8,128,1,1,256] f32
// One 256-thread block (4 waves) per box = 1024 blocks = exactly 4 blocks/CU.
// Prologue: threads 0..83 build per-sample-point LDS tables (folded bilinear
// weights incl. validity, precomputed element offsets). Main loop: wave w
// handles points p = w + 4*it, it in [0,21) -- fully unrolled, BRANCH-FREE:
// 2 broadcast ds_read_b128 + 4 independent global_load_dwordx4 + FMA per point,
// so loads pipeline deeply instead of stalling behind per-point guards.
// Points 81..83 are padding with zero weights (read point 80's addresses).

#define BATCH 8
#define NBOX  128
#define IH    64
#define IW    64
#define IC    2304
#define SCH   256            // IC / 9
#define HWIC  (IH * IW * IC)

typedef float f32x4 __attribute__((ext_vector_type(4)));

__global__ __launch_bounds__(256) void psroi_kernel(
    const float* __restrict__ inp,
    const float* __restrict__ boxes,
    float* __restrict__ out)
{
    const int blk  = blockIdx.x;
    const int b    = blk & 7;      // image (XCD-aligned)
    const int n    = blk >> 3;     // box within image
    const int box  = b * NBOX + n;
    const int tid  = threadIdx.x;
    const int lane = tid & 63;     // channel group: 4*lane..4*lane+3
    const int w    = tid >> 6;     // wave 0..3 -> point stripe

    __shared__ f32x4 wtab[84];     // {wy0, wy1, wx0, wx1} (validity folded in)
    __shared__ int4  itab[84];     // {row0_off, row1_off, col0_off, col1_off} (elements)
    __shared__ float red[4][SCH];

    if (tid < 84) {
        const int   pc = (tid <= 80) ? tid : 80;
        const float en = (tid <= 80) ? 1.0f : 0.0f;   // zero-weight padding

        // decode point pc -> bin (by,bx), sample (cy,cx)
        const int tb  = pc / 9;
        const int rem = pc - 9 * tb;
        const int cy  = rem / 3;
        const int cx  = rem - 3 * cy;
        const int by  = tb / 3;
        const int bx  = tb - 3 * by;

        const float* bp = boxes + (size_t)box * 4;
        const float y1 = bp[0];
        const float x1 = bp[1];
        const float y2 = bp[2];
        const float x2 = bp[3];
        const float sy = (y2 - y1) * (1.0f / 3.0f);
        const float sx = (x2 - x1) * (1.0f / 3.0f);

        const float ys = (y1 + (float)by * sy) * 63.0f + (float)cy * sy * 31.5f;
        const float xs = (x1 + (float)bx * sx) * 63.0f + (float)cx * sx * 31.5f;

        const float vy = (ys >= 0.0f && ys <= 63.0f) ? en : 0.0f;
        const float vx = (xs >= 0.0f && xs <= 63.0f) ? 1.0f : 0.0f;

        const float ysc = fminf(fmaxf(ys, 0.0f), 63.0f);
        const float xsc = fminf(fmaxf(xs, 0.0f), 63.0f);
        const float yf = floorf(ysc);
        const float xf = floorf(xsc);
        const float ly = ysc - yf;
        const float lx = xsc - xf;

        const int y0 = (int)yf;
        const int y1r = (y0 + 1 < 63) ? (y0 + 1) : 63;
        const int x0 = (int)xf;
        const int x1c = (x0 + 1 < 63) ? (x0 + 1) : 63;

        f32x4 wv;
        wv.x = (1.0f - ly) * vy;   // wy0
        wv.y = ly * vy;            // wy1
        wv.z = (1.0f - lx) * vx;   // wx0
        wv.w = lx * vx;            // wx1
        wtab[tid] = wv;

        int4 io;
        io.x = y0  * (IW * IC) + tb * SCH;   // row0 element offset (+ bin channel group)
        io.y = y1r * (IW * IC) + tb * SCH;   // row1
        io.z = x0  * IC;                      // col0
        io.w = x1c * IC;                      // col1
        itab[tid] = io;
    }
    __syncthreads();

    const float* base = inp + (size_t)b * HWIC + lane * 4;

    f32x4 acc = {0.0f, 0.0f, 0.0f, 0.0f};

    #pragma unroll
    for (int it = 0; it < 21; ++it) {
        const int p = w + 4 * it;          // wave-uniform
        const f32x4 wv = wtab[p];          // broadcast ds_read_b128
        const int4  io = itab[p];          // broadcast ds_read_b128
        const f32x4 A = *reinterpret_cast<const f32x4*>(base + io.x + io.z);
        const f32x4 B = *reinterpret_cast<const f32x4*>(base + io.x + io.w);
        const f32x4 C = *reinterpret_cast<const f32x4*>(base + io.y + io.z);
        const f32x4 D = *reinterpret_cast<const f32x4*>(base + io.y + io.w);
        acc += (A * wv.z + B * wv.w) * wv.x + (C * wv.z + D * wv.w) * wv.y;
    }

    // Reduce 4 waves' partial sums via LDS.
    *reinterpret_cast<f32x4*>(&red[w][lane * 4]) = acc;
    __syncthreads();

    const float v = (red[0][tid] + red[1][tid]) + (red[2][tid] + red[3][tid]);
    out[(size_t)box * SCH + tid] = v * (1.0f / 81.0f);
}

extern "C" void kernel_launch(void* const* d_in, const int* in_sizes, int n_in,
                              void* d_out, int out_size, void* d_ws, size_t ws_size,
                              hipStream_t stream) {
    const float* inp   = (const float*)d_in[0];
    const float* boxes = (const float*)d_in[1];
    float* out = (float*)d_out;

    dim3 grid(BATCH * NBOX);
    dim3 block(256);
    psroi_kernel<<<grid, block, 0, stream>>>(inp, boxes, out);
}

// Round 6
// 29.727 us; speedup vs baseline: 1.2811x; 1.1599x over previous
//
#include <hip/hip_runtime.h>

// PS-ROI pooling. inputs: [8,64,64,2304] f32 ; boxes: [8,128,4] f32
// out: [8,128,1,1,256] f32
// One 256-thread block (4 waves) per box = 1024 blocks = exactly 4 blocks/CU
// (launch_bounds caps VGPR<=128 so all 4 blocks co-reside -> 16 waves/CU).
// Prologue: every thread computes folded per-axis weight/offset tables in
// REGISTERS (validity folded in as multiplier -> no guards needed).
// Main loop: one wave-uniform 4-way switch on wave id, then each stripe is a
// fully-unrolled straight-line body (compile-time point ids -> register
// indexing stays register-allocated): 4 independent global_load_dwordx4 + FMA
// per point, zero branches -> deep load pipelining.

#define BATCH 8
#define NBOX  128
#define IH    64
#define IW    64
#define IC    2304
#define SCH   256            // IC / 9
#define HWIC  (IH * IW * IC)

typedef float f32x4 __attribute__((ext_vector_type(4)));

__global__ __launch_bounds__(256, 4) void psroi_kernel(
    const float* __restrict__ inp,
    const float* __restrict__ boxes,
    float* __restrict__ out)
{
    const int blk  = blockIdx.x;
    const int b    = blk & 7;      // image (XCD-aligned)
    const int n    = blk >> 3;     // box within image
    const int box  = b * NBOX + n;
    const int tid  = threadIdx.x;
    const int lane = tid & 63;     // channel group: 4*lane..4*lane+3
    const int w    = tid >> 6;     // wave 0..3 -> point stripe

    const float* bp = boxes + (size_t)box * 4;
    const float by1 = bp[0];
    const float bx1 = bp[1];
    const float by2 = bp[2];
    const float bx2 = bp[3];
    const float sy = (by2 - by1) * (1.0f / 3.0f);
    const float sx = (bx2 - bx1) * (1.0f / 3.0f);

    // Per-axis tables (registers; indices below are all compile-time).
    float wy0t[9], wy1t[9], wx0t[9], wx1t[9];
    int   r0t[9], c0t[9];

    #pragma unroll
    for (int byi = 0; byi < 3; ++byi) {
        #pragma unroll
        for (int i = 0; i < 3; ++i) {
            const int j = byi * 3 + i;
            const float ys = (by1 + (float)byi * sy) * 63.0f + (float)i * sy * 31.5f;
            const float xs = (bx1 + (float)byi * sx) * 63.0f + (float)i * sx * 31.5f;
            const float vy = (ys >= 0.0f && ys <= 63.0f) ? 1.0f : 0.0f;
            const float vx = (xs >= 0.0f && xs <= 63.0f) ? 1.0f : 0.0f;
            const float ysc = fminf(fmaxf(ys, 0.0f), 63.0f);
            const float xsc = fminf(fmaxf(xs, 0.0f), 63.0f);
            const float yf = floorf(ysc);
            const float xf = floorf(xsc);
            const float ly = ysc - yf;
            const float lx = xsc - xf;
            wy0t[j] = (1.0f - ly) * vy;
            wy1t[j] = ly * vy;
            wx0t[j] = (1.0f - lx) * vx;
            wx1t[j] = lx * vx;
            r0t[j]  = (int)yf * IW;
            c0t[j]  = (int)xf;
        }
    }

    const float* base = inp + (size_t)b * HWIC + lane * 4;

    f32x4 acc = {0.0f, 0.0f, 0.0f, 0.0f};

    // P_(p): p is a compile-time constant -> all table indices fold.
    #define P_(p) do {                                                         \
        const int tb_ = (p) / 9;                                               \
        const int rm_ = (p) - 9 * tb_;                                         \
        const int cy_ = rm_ / 3;                                               \
        const int cx_ = rm_ - 3 * cy_;                                         \
        const int jy_ = (tb_ / 3) * 3 + cy_;                                   \
        const int jx_ = (tb_ - 3 * (tb_ / 3)) * 3 + cx_;                       \
        const int rr0 = r0t[jy_];                                              \
        const int rr1 = (rr0 < 63 * IW) ? rr0 + IW : rr0;                      \
        const int cc0 = c0t[jx_];                                              \
        const int cc1 = (cc0 < 63) ? cc0 + 1 : cc0;                            \
        const float wy0 = wy0t[jy_], wy1 = wy1t[jy_];                          \
        const float wx0 = wx0t[jx_], wx1 = wx1t[jx_];                          \
        const float* gb = base + tb_ * SCH;                                    \
        const f32x4 A = *reinterpret_cast<const f32x4*>(gb + (size_t)(rr0 + cc0) * IC); \
        const f32x4 B = *reinterpret_cast<const f32x4*>(gb + (size_t)(rr0 + cc1) * IC); \
        const f32x4 C = *reinterpret_cast<const f32x4*>(gb + (size_t)(rr1 + cc0) * IC); \
        const f32x4 D = *reinterpret_cast<const f32x4*>(gb + (size_t)(rr1 + cc1) * IC); \
        acc += (A * wx0 + B * wx1) * wy0 + (C * wx0 + D * wx1) * wy1;          \
    } while (0)

    // Stripe W: points W, W+4, ..., <=80. Wave-uniform single branch.
    if (w == 0) {
        P_(0);  P_(4);  P_(8);  P_(12); P_(16); P_(20); P_(24); P_(28);
        P_(32); P_(36); P_(40); P_(44); P_(48); P_(52); P_(56); P_(60);
        P_(64); P_(68); P_(72); P_(76); P_(80);
    } else if (w == 1) {
        P_(1);  P_(5);  P_(9);  P_(13); P_(17); P_(21); P_(25); P_(29);
        P_(33); P_(37); P_(41); P_(45); P_(49); P_(53); P_(57); P_(61);
        P_(65); P_(69); P_(73); P_(77);
    } else if (w == 2) {
        P_(2);  P_(6);  P_(10); P_(14); P_(18); P_(22); P_(26); P_(30);
        P_(34); P_(38); P_(42); P_(46); P_(50); P_(54); P_(58); P_(62);
        P_(66); P_(70); P_(74); P_(78);
    } else {
        P_(3);  P_(7);  P_(11); P_(15); P_(19); P_(23); P_(27); P_(31);
        P_(35); P_(39); P_(43); P_(47); P_(51); P_(55); P_(59); P_(63);
        P_(67); P_(71); P_(75); P_(79);
    }
    #undef P_

    // Reduce 4 waves' partial sums via LDS.
    __shared__ float red[4][SCH];
    *reinterpret_cast<f32x4*>(&red[w][lane * 4]) = acc;
    __syncthreads();

    const float v = (red[0][tid] + red[1][tid]) + (red[2][tid] + red[3][tid]);
    out[(size_t)box * SCH + tid] = v * (1.0f / 81.0f);
}

extern "C" void kernel_launch(void* const* d_in, const int* in_sizes, int n_in,
                              void* d_out, int out_size, void* d_ws, size_t ws_size,
                              hipStream_t stream) {
    const float* inp   = (const float*)d_in[0];
    const float* boxes = (const float*)d_in[1];
    float* out = (float*)d_out;

    dim3 grid(BATCH * NBOX);
    dim3 block(256);
    psroi_kernel<<<grid, block, 0, stream>>>(inp, boxes, out);
}